// Round 1
// baseline (451.889 us; speedup 1.0000x reference)
//
#include <hip/hip_runtime.h>

// Problem constants (from reference)
#define B_    8
#define A_    60000
#define C_    150        // 1 + 10+19+39+69+12
#define G_    20
#define T_    5
#define ROWS  21         // G+1 (row 0 = pad/zero row)
#define NANCH (B_ * A_)          // 480000
#define NTOT  (B_ * A_ * C_)     // 72,000,000
#define TABN  (B_ * ROWS * C_)   // 25200
#define BETA_ (1.0f / 9.0f)

// ---------------------------------------------------------------------------
// Kernel 1: build the 0/1 label table textab[b][g][c] and zero accumulators.
//   c==0       : label for the binary head = (g>0)  (pos <=> idx>0)
//   c in head i: 1 iff any of the T gt labels for (b, g-1, head i) equals class
//   g==0       : all zeros (the padded row; also covers labels_bin in {-1,0})
// ---------------------------------------------------------------------------
__global__ void build_table(const int* __restrict__ gt_labels,
                            float* __restrict__ tab,
                            float* __restrict__ accum) {
    int i = blockIdx.x * blockDim.x + threadIdx.x;
    if (i < 4) accum[i] = 0.0f;          // [0]=reg_sum [1]=cls_sum [2]=pos_cnt
    if (i >= TABN) return;
    int c  = i % C_;
    int bg = i / C_;
    int g  = bg % ROWS;
    int b  = bg / ROWS;
    float v = 0.0f;
    if (g > 0) {
        if (c == 0) {
            v = 1.0f;
        } else {
            int cc = c - 1;   // offsets: 0,10,29,68,137 ; sizes 10,19,39,69,12
            int head, k;
            if      (cc < 10)  { head = 0; k = cc; }
            else if (cc < 29)  { head = 1; k = cc - 10; }
            else if (cc < 68)  { head = 2; k = cc - 29; }
            else if (cc < 137) { head = 3; k = cc - 68; }
            else               { head = 4; k = cc - 137; }
            const int* lp = gt_labels + ((b * G_ + (g - 1)) * 5 + head) * T_;
            // invalid labels are -1 and never equal k>=0 (matches the
            // valid-mask * one_hot construction in the reference)
            v = (lp[0] == k || lp[1] == k || lp[2] == k ||
                 lp[3] == k || lp[4] == k) ? 1.0f : 0.0f;
        }
    }
    tab[i] = v;
}

// Block-wide sum; result valid only in threadIdx.x == 0. Block = 256 (4 waves).
__device__ __forceinline__ float block_reduce_sum(float v, float* sm) {
    #pragma unroll
    for (int off = 32; off > 0; off >>= 1) v += __shfl_down(v, off, 64);
    int lane = threadIdx.x & 63, w = threadIdx.x >> 6;
    if (lane == 0) sm[w] = v;
    __syncthreads();
    float r = 0.0f;
    if (threadIdx.x == 0) r = sm[0] + sm[1] + sm[2] + sm[3];
    __syncthreads();
    return r;
}

// ---------------------------------------------------------------------------
// Kernel 2: smooth-L1 regression sum over positive anchors + positive count.
// ---------------------------------------------------------------------------
__device__ __forceinline__ float sl1(float n) {
    return (n < BETA_) ? (0.5f / BETA_) * n * n : n - 0.5f * BETA_;
}

__global__ __launch_bounds__(256) void reg_kernel(
        const float* __restrict__ pred, const float* __restrict__ gt,
        const int* __restrict__ lb, float* __restrict__ accum) {
    __shared__ float sm[4];
    float reg = 0.0f, cnt = 0.0f;
    int stride = gridDim.x * blockDim.x;
    for (int a = blockIdx.x * blockDim.x + threadIdx.x; a < NANCH; a += stride) {
        int l = lb[a];
        if (l > 0) {
            cnt += 1.0f;
            float4 p = ((const float4*)pred)[a];
            float4 g = ((const float4*)gt)[a];
            reg += sl1(fabsf(p.x - g.x)) + sl1(fabsf(p.y - g.y)) +
                   sl1(fabsf(p.z - g.z)) + sl1(fabsf(p.w - g.w));
        }
    }
    float rblk = block_reduce_sum(reg, sm);
    float cblk = block_reduce_sum(cnt, sm);
    if (threadIdx.x == 0) {
        atomicAdd(&accum[0], rblk);
        atomicAdd(&accum[2], cblk);
    }
}

// ---------------------------------------------------------------------------
// Kernel 3: focal cls sum over all 72M confidence elements (float4 chunks).
// For label L in {0,1}: with s = L ? x : -x,
//   term = mask * (L ? 0.25 : 0.75) * (1 - sigmoid(s))^2 * log(1 + exp(-s))
// (clip at 1e-7 is dead for |x| <~ 6; inputs are N(0,1))
// ---------------------------------------------------------------------------
__global__ __launch_bounds__(256) void cls_kernel(
        const float* __restrict__ conf, const int* __restrict__ lb,
        const float* __restrict__ tab, float* __restrict__ accum) {
    __shared__ float sm[4];
    float acc = 0.0f;
    const float4* cp = (const float4*)conf;
    const int nchunks = NTOT / 4;                 // 18,000,000
    int stride = gridDim.x * blockDim.x;
    for (int ch = blockIdx.x * blockDim.x + threadIdx.x; ch < nchunks; ch += stride) {
        int e = ch * 4;
        float4 x = cp[ch];
        int a  = e / C_;                          // magic-mul div by 150
        int c  = e - a * C_;
        int l0 = lb[a];
        int b0 = a / A_;
        int row0 = (b0 * ROWS + max(l0, 0)) * C_;
        float m0 = (l0 > -1) ? 1.0f : 0.0f;
        int row1 = row0; float m1 = m0;
        if (c + 3 >= C_) {                        // chunk spans into anchor a+1
            int l1 = lb[a + 1];
            int b1 = (a + 1) / A_;
            row1 = (b1 * ROWS + max(l1, 0)) * C_;
            m1 = (l1 > -1) ? 1.0f : 0.0f;
        }
        float xs[4] = {x.x, x.y, x.z, x.w};
        #pragma unroll
        for (int j = 0; j < 4; ++j) {
            int cj = c + j;
            int rb; float mf;
            if (cj < C_) { rb = row0 + cj;      mf = m0; }
            else         { rb = row1 + cj - C_; mf = m1; }
            float L = tab[rb];
            float s = (L + L - 1.0f) * xs[j];
            float t = __expf(-s);
            float denom = 1.0f + t;
            float inv = __builtin_amdgcn_rcpf(denom);
            float om  = t * inv;                  // 1 - sigmoid(s)
            float ld  = __logf(denom);            // log(1 + exp(-s))
            acc += mf * fmaf(L, -0.5f, 0.75f) * (om * om) * ld;
        }
    }
    float blk = block_reduce_sum(acc, sm);
    if (threadIdx.x == 0) atomicAdd(&accum[1], blk);
}

// ---------------------------------------------------------------------------
// Kernel 4: finalize the two scalar outputs.
// ---------------------------------------------------------------------------
__global__ void finalize(const float* __restrict__ accum, float* __restrict__ out) {
    float np = fmaxf(1.0f, accum[2]);
    out[0] = accum[0] / (np * 4.0f);
    out[1] = accum[1] / (np * 6.0f);
}

extern "C" void kernel_launch(void* const* d_in, const int* in_sizes, int n_in,
                              void* d_out, int out_size, void* d_ws, size_t ws_size,
                              hipStream_t stream) {
    const float* conf = (const float*)d_in[0];
    const float* pred = (const float*)d_in[1];
    const float* gt   = (const float*)d_in[2];
    const int*   gtl  = (const int*)d_in[3];
    // d_in[4] = counts: unused by the reference computation
    const int*   lb   = (const int*)d_in[5];
    float* out   = (float*)d_out;
    float* accum = (float*)d_ws;            // 4 floats
    float* tab   = (float*)d_ws + 64;       // 25200 floats (100 KB)

    build_table<<<(TABN + 255) / 256, 256, 0, stream>>>(gtl, tab, accum);
    reg_kernel<<<512, 256, 0, stream>>>(pred, gt, lb, accum);
    cls_kernel<<<4096, 256, 0, stream>>>(conf, lb, tab, accum);
    finalize<<<1, 1, 0, stream>>>(accum, out);
}

// Round 2
// 441.939 us; speedup vs baseline: 1.0225x; 1.0225x over previous
//
#include <hip/hip_runtime.h>

// Problem constants (from reference)
#define B_    8
#define A_    60000
#define C_    150        // 1 + 10+19+39+69+12
#define G_    20
#define T_    5
#define ROWS  21         // G+1 (row 0 = pad/zero row)
#define NANCH (B_ * A_)          // 480000
#define NTOT  (B_ * A_ * C_)     // 72,000,000
#define TABN  (B_ * ROWS * C_)   // 25200
#define BETA_ (1.0f / 9.0f)

// ---------------------------------------------------------------------------
// Kernel 1: build the 0/1 label table tab[b][g][c] and zero accumulators.
//   c==0       : label for the binary head = (g>0)  (pos <=> idx>0)
//   c in head i: 1 iff any of the T gt labels for (b, g-1, head i) equals class
//   g==0       : all zeros (pad row; also covers labels_bin in {-1,0})
// ---------------------------------------------------------------------------
__global__ void build_table(const int* __restrict__ gt_labels,
                            float* __restrict__ tab,
                            float* __restrict__ accum) {
    int i = blockIdx.x * blockDim.x + threadIdx.x;
    if (i < 4) accum[i] = 0.0f;          // [0]=reg_sum [1]=cls_sum [2]=pos_cnt
    if (i >= TABN) return;
    int c  = i % C_;
    int bg = i / C_;
    int g  = bg % ROWS;
    int b  = bg / ROWS;
    float v = 0.0f;
    if (g > 0) {
        if (c == 0) {
            v = 1.0f;
        } else {
            int cc = c - 1;   // head offsets: 0,10,29,68,137 ; sizes 10,19,39,69,12
            int head, k;
            if      (cc < 10)  { head = 0; k = cc; }
            else if (cc < 29)  { head = 1; k = cc - 10; }
            else if (cc < 68)  { head = 2; k = cc - 29; }
            else if (cc < 137) { head = 3; k = cc - 68; }
            else               { head = 4; k = cc - 137; }
            const int* lp = gt_labels + ((b * G_ + (g - 1)) * 5 + head) * T_;
            v = (lp[0] == k || lp[1] == k || lp[2] == k ||
                 lp[3] == k || lp[4] == k) ? 1.0f : 0.0f;
        }
    }
    tab[i] = v;
}

// Block-wide sum; result valid only in threadIdx.x == 0. Block = 256 (4 waves).
__device__ __forceinline__ float block_reduce_sum(float v, float* sm) {
    #pragma unroll
    for (int off = 32; off > 0; off >>= 1) v += __shfl_down(v, off, 64);
    int lane = threadIdx.x & 63, w = threadIdx.x >> 6;
    if (lane == 0) sm[w] = v;
    __syncthreads();
    float r = 0.0f;
    if (threadIdx.x == 0) r = sm[0] + sm[1] + sm[2] + sm[3];
    __syncthreads();
    return r;
}

// ---------------------------------------------------------------------------
// Kernel 2: smooth-L1 regression sum over positive anchors + positive count.
// ---------------------------------------------------------------------------
__device__ __forceinline__ float sl1(float n) {
    return (n < BETA_) ? (0.5f / BETA_) * n * n : n - 0.5f * BETA_;
}

__global__ __launch_bounds__(256) void reg_kernel(
        const float* __restrict__ pred, const float* __restrict__ gt,
        const int* __restrict__ lb, float* __restrict__ accum) {
    __shared__ float sm[4];
    float reg = 0.0f, cnt = 0.0f;
    int stride = gridDim.x * blockDim.x;
    for (int a = blockIdx.x * blockDim.x + threadIdx.x; a < NANCH; a += stride) {
        int l = lb[a];
        if (l > 0) {
            cnt += 1.0f;
            float4 p = ((const float4*)pred)[a];
            float4 g = ((const float4*)gt)[a];
            reg += sl1(fabsf(p.x - g.x)) + sl1(fabsf(p.y - g.y)) +
                   sl1(fabsf(p.z - g.z)) + sl1(fabsf(p.w - g.w));
        }
    }
    float rblk = block_reduce_sum(reg, sm);
    float cblk = block_reduce_sum(cnt, sm);
    if (threadIdx.x == 0) {
        atomicAdd(&accum[0], rblk);
        atomicAdd(&accum[2], cblk);
    }
}

// ---------------------------------------------------------------------------
// Kernel 3: focal cls sum over all 72M confidence elements (float4 chunks).
// For label L in {0,1}: with s = L ? x : -x,
//   term = mask * (L ? 0.25 : 0.75) * (1 - sigmoid(s))^2 * log(1 + exp(-s))
// labels_bin distribution: 90% 0 / 5% -1 / 5% pos. l<=0 selects the all-zero
// pad row, so only l>0 anchors (~5%) ever touch the table -> three paths:
//   l==0 : L=0 closed form, no gather         (90% of anchors)
//   l==-1: mask=0, contribute nothing          (5%)
//   l> 0 : per-element table gather            (5%)
// ---------------------------------------------------------------------------
__global__ __launch_bounds__(256) void cls_kernel(
        const float* __restrict__ conf, const int* __restrict__ lb,
        const float* __restrict__ tab, float* __restrict__ accum) {
    __shared__ float sm[4];
    float acc = 0.0f;
    const float4* cp = (const float4*)conf;
    const int nchunks = NTOT / 4;                 // 18,000,000
    int stride = gridDim.x * blockDim.x;
    for (int ch = blockIdx.x * blockDim.x + threadIdx.x; ch < nchunks; ch += stride) {
        int e = ch * 4;
        float4 x = cp[ch];
        int a  = e / C_;                          // magic-mul div by 150
        int c  = e - a * C_;
        int l0 = lb[a];
        bool spans = (c + 3 >= C_);               // chunk crosses into anchor a+1
        int l1 = spans ? lb[a + 1] : l0;

        if ((l0 | l1) == 0) {
            // ---- fast path: all labels 0, mask 1 (w = 0.75) ----
            float xs[4] = {x.x, x.y, x.z, x.w};
            #pragma unroll
            for (int j = 0; j < 4; ++j) {
                float t = __expf(xs[j]);          // exp(x)
                float denom = 1.0f + t;
                float om = t * __builtin_amdgcn_rcpf(denom);   // sigmoid(x)
                acc += 0.75f * (om * om) * __logf(denom);
            }
        } else if (l0 == -1 && l1 == -1) {
            // ---- ignored anchors: mask 0 ----
        } else {
            // ---- general path (rare): table gather per element ----
            int b0 = a / A_;
            int row0 = (b0 * ROWS + max(l0, 0)) * C_;
            float m0 = (l0 > -1) ? 1.0f : 0.0f;
            int row1 = row0; float m1 = m0;
            if (spans) {
                int b1 = (a + 1) / A_;
                row1 = (b1 * ROWS + max(l1, 0)) * C_;
                m1 = (l1 > -1) ? 1.0f : 0.0f;
            }
            float xs[4] = {x.x, x.y, x.z, x.w};
            #pragma unroll
            for (int j = 0; j < 4; ++j) {
                int cj = c + j;
                int rb; float mf;
                if (cj < C_) { rb = row0 + cj;      mf = m0; }
                else         { rb = row1 + cj - C_; mf = m1; }
                float L = tab[rb];
                float s = (L + L - 1.0f) * xs[j];
                float t = __expf(-s);
                float denom = 1.0f + t;
                float om  = t * __builtin_amdgcn_rcpf(denom);  // 1 - sigmoid(s)
                float ld  = __logf(denom);                     // log(1 + exp(-s))
                acc += mf * fmaf(L, -0.5f, 0.75f) * (om * om) * ld;
            }
        }
    }
    float blk = block_reduce_sum(acc, sm);
    if (threadIdx.x == 0) atomicAdd(&accum[1], blk);
}

// ---------------------------------------------------------------------------
// Kernel 4: finalize the two scalar outputs.
// ---------------------------------------------------------------------------
__global__ void finalize(const float* __restrict__ accum, float* __restrict__ out) {
    float np = fmaxf(1.0f, accum[2]);
    out[0] = accum[0] / (np * 4.0f);
    out[1] = accum[1] / (np * 6.0f);
}

extern "C" void kernel_launch(void* const* d_in, const int* in_sizes, int n_in,
                              void* d_out, int out_size, void* d_ws, size_t ws_size,
                              hipStream_t stream) {
    const float* conf = (const float*)d_in[0];
    const float* pred = (const float*)d_in[1];
    const float* gt   = (const float*)d_in[2];
    const int*   gtl  = (const int*)d_in[3];
    // d_in[4] = counts: unused by the reference computation
    const int*   lb   = (const int*)d_in[5];
    float* out   = (float*)d_out;
    float* accum = (float*)d_ws;            // 4 floats
    float* tab   = (float*)d_ws + 64;       // 25200 floats (100 KB)

    build_table<<<(TABN + 255) / 256, 256, 0, stream>>>(gtl, tab, accum);
    reg_kernel<<<512, 256, 0, stream>>>(pred, gt, lb, accum);
    cls_kernel<<<4096, 256, 0, stream>>>(conf, lb, tab, accum);
    finalize<<<1, 1, 0, stream>>>(accum, out);
}